// Round 1
// baseline (95.119 us; speedup 1.0000x reference)
//
#include <hip/hip_runtime.h>

// Shapes (fixed by setup_inputs): T=8, S=512, B=8, D=512, H=8, hd=64, BH=64
// NE=32, NI=64.  out: (64, 512, 512) f32.
//
// Math reduction: sum_p telescopes to (sum_t Q_t)(sum_t K_t)^T * scale, so
//   p = (Xsum@Wq^T + 8 bq)(Xsum@Wk^T + 8 bk)^T / 64   (per bh batch, hd=64)
// then the elementwise MLP epilogue + row reductions, fused per 64-row tile.

#define T_  8
#define S_  512
#define B_  8
#define D_  512
#define NE_ 32
#define NI_ 64

typedef __attribute__((ext_vector_type(8))) short bf16x8;
typedef __attribute__((ext_vector_type(4))) float f32x4;

// workspace layout, in ushort elements
#define XS_OFF 0u        // Xsum bf16 (4096 x 512)
#define WQ_OFF 2097152u  // Wq bf16 (512 x 512)
#define WK_OFF 2359296u  // Wk bf16
#define QB_OFF 2621440u  // Q bf16 (64, 512, 64)
#define KB_OFF 4718592u  // K bf16 (64, 512, 64)

__device__ inline unsigned short f2bf(float f) {
  union { float f; unsigned u; } v; v.f = f;
  unsigned r = v.u + 0x7FFFu + ((v.u >> 16) & 1u);
  return (unsigned short)(r >> 16);
}

__device__ inline void gload16(const void* g, void* l) {
  __builtin_amdgcn_global_load_lds(
      (const __attribute__((address_space(1))) void*)g,
      (__attribute__((address_space(3))) void*)l, 16, 0, 0);
}

// LDS tiles are row-major with 128-byte rows (64 bf16). Unswizzled, a
// 16-lane column read is a 16-way bank conflict (G4), so slots are XORed
// with (row&7); the global source is pre-swizzled to match (rule 21c).
__device__ inline bf16x8 lds_read_swz(const unsigned short* base, int row, int byteoff) {
  int addr = row * 128 + (byteoff ^ ((row & 7) << 4));
  return *(const bf16x8*)((const char*)base + addr);
}

__device__ inline float invmlp(float x, const float* __restrict__ w1,
                               const float* __restrict__ b1,
                               const float* __restrict__ w2, float b2) {
  float a = b2;
  for (int n = 0; n < NI_; n++) a += w2[n] * fmaxf(x * w1[n] + b1[n], 0.0f);
  return a;
}

// ---------------------------------------------------------------------------
// Kernel 1: Xsum = sum_t sx[t]  (f32 -> bf16), plus Wq/Wk f32 -> bf16 casts.
// blocks 0..2047: xsum (2M elems, 4/thread); 2048..2303: Wq; 2304..2559: Wk.
__global__ __launch_bounds__(256) void k_pre(
    const float* __restrict__ sx, const float* __restrict__ wq,
    const float* __restrict__ wk, unsigned short* __restrict__ xs,
    unsigned short* __restrict__ wqb, unsigned short* __restrict__ wkb) {
  int bx = blockIdx.x, tid = threadIdx.x;
  if (bx < 2048) {
    size_t i = ((size_t)bx * 256 + tid) * 4;
    float4 a = *(const float4*)(sx + i);
#pragma unroll
    for (int t = 1; t < T_; t++) {
      float4 v = *(const float4*)(sx + (size_t)t * 2097152 + i);
      a.x += v.x; a.y += v.y; a.z += v.z; a.w += v.w;
    }
    ushort4 o; o.x = f2bf(a.x); o.y = f2bf(a.y); o.z = f2bf(a.z); o.w = f2bf(a.w);
    *(ushort4*)(xs + i) = o;
  } else {
    const float* src = (bx < 2304) ? wq : wk;
    unsigned short* dst = (bx < 2304) ? wqb : wkb;
    int base = (bx < 2304) ? 2048 : 2304;
    size_t i = ((size_t)(bx - base) * 256 + tid) * 4;
    float4 a = *(const float4*)(src + i);
    ushort4 o; o.x = f2bf(a.x); o.y = f2bf(a.y); o.z = f2bf(a.z); o.w = f2bf(a.w);
    *(ushort4*)(dst + i) = o;
  }
}

// ---------------------------------------------------------------------------
// Kernel 2: Y = Xsum(4096x512) @ W^T + 8*bias, stored as bf16 in (bh, s, dh)
// layout.  grid (32, 4, 2): 128x128 tile, z selects Q/K.  4 waves, 64x64 each.
__global__ __launch_bounds__(256, 2) void k_proj(
    const unsigned short* __restrict__ xs, const unsigned short* __restrict__ wb,
    const float* __restrict__ bq, const float* __restrict__ bk,
    unsigned short* __restrict__ outb) {
  __shared__ unsigned short As[128 * 64];
  __shared__ unsigned short Bs[128 * 64];
  int tid = threadIdx.x;
  int lane = tid & 63, w = tid >> 6;
  int r0 = blockIdx.x * 128;
  int c0 = blockIdx.y * 128;
  int z = blockIdx.z;
  const unsigned short* W = wb + (size_t)z * 262144;
  const float* bias = z ? bk : bq;
  unsigned short* dst = outb + (size_t)z * 2097152;

  int rgrp = lane >> 4, cl = lane & 15;
  int r0w = (w >> 1) * 64, c0w = (w & 1) * 64;

  f32x4 acc[4][4];
  f32x4 zero = {0.f, 0.f, 0.f, 0.f};
#pragma unroll
  for (int m = 0; m < 4; m++)
#pragma unroll
    for (int n = 0; n < 4; n++) acc[m][n] = zero;

  int rl = lane >> 3, slot = lane & 7;

  for (int kt = 0; kt < 8; kt++) {
    int k0 = kt * 64;
#pragma unroll
    for (int i = 0; i < 4; i++) {
      int chunk = w * 4 + i;
      int r = chunk * 8 + rl;
      int sw = (slot ^ (r & 7)) * 8;
      gload16(xs + (size_t)(r0 + r) * 512 + k0 + sw, (char*)As + chunk * 1024);
      gload16(W + (size_t)(c0 + r) * 512 + k0 + sw, (char*)Bs + chunk * 1024);
    }
    __syncthreads();
#pragma unroll
    for (int kb = 0; kb < 2; kb++) {
      bf16x8 af[4], bfr[4];
#pragma unroll
      for (int m = 0; m < 4; m++) af[m] = lds_read_swz(As, r0w + 16 * m + cl, kb * 64 + rgrp * 16);
#pragma unroll
      for (int n = 0; n < 4; n++) bfr[n] = lds_read_swz(Bs, c0w + 16 * n + cl, kb * 64 + rgrp * 16);
#pragma unroll
      for (int m = 0; m < 4; m++)
#pragma unroll
        for (int n = 0; n < 4; n++)
          acc[m][n] = __builtin_amdgcn_mfma_f32_16x16x32_bf16(af[m], bfr[n], acc[m][n], 0, 0, 0);
    }
    __syncthreads();
  }

  // epilogue: +8*bias, cast, scatter into (b*8+h, s, dh) layout
#pragma unroll
  for (int n = 0; n < 4; n++) {
    int cg = c0 + c0w + 16 * n + cl;
    float bv = 8.0f * bias[cg];
    int h = cg >> 6, dh = cg & 63;
#pragma unroll
    for (int m = 0; m < 4; m++) {
#pragma unroll
      for (int j = 0; j < 4; j++) {
        int rg = r0 + r0w + 16 * m + rgrp * 4 + j;
        int s = rg >> 3, b = rg & 7;
        dst[((size_t)(b * 8 + h) * 512 + s) * 64 + dh] = f2bf(acc[m][n][j] + bv);
      }
    }
  }
}

// ---------------------------------------------------------------------------
// Kernel 3: per (row-tile rt, batch bh): P = Q(64x64) K(512x64)^T / 64,
// then fused epilogue (tmax, exp-MLP, row sums, inv-MLP factors, store).
// grid (8, 64), 512 threads = 8 waves: wave = (rowstripe 0..3) x (colhalf 0..1)
__global__ __launch_bounds__(512, 2) void k_attn(
    const unsigned short* __restrict__ qb, const unsigned short* __restrict__ kb,
    const float* __restrict__ ew1, const float* __restrict__ eb1,
    const float* __restrict__ ew2, const float* __restrict__ eb2p,
    const float* __restrict__ iw1, const float* __restrict__ ib1,
    const float* __restrict__ iw2, const float* __restrict__ ib2p,
    float* __restrict__ out) {
  __shared__ unsigned short Ks[512 * 64];  // 64 KB
  __shared__ unsigned short Qs[64 * 64];   // 8 KB
  __shared__ float s_tmax[64];
  __shared__ float s_part[2][64];
  __shared__ float s_fac[64];

  int tid = threadIdx.x;
  int lane = tid & 63, w = tid >> 6;
  int rt = blockIdx.x, bh = blockIdx.y;

  const unsigned short* Kg = kb + (size_t)bh * (512 * 64);
  const unsigned short* Qg = qb + ((size_t)bh * 512 + rt * 64) * 64;

  int rl = lane >> 3, slot = lane & 7;
#pragma unroll
  for (int i = 0; i < 8; i++) {
    int chunk = w * 8 + i;
    int r = chunk * 8 + rl;
    int sw = (slot ^ (r & 7)) * 8;
    gload16(Kg + (size_t)r * 64 + sw, (char*)Ks + chunk * 1024);
  }
  {
    int r = w * 8 + rl;
    int sw = (slot ^ (r & 7)) * 8;
    gload16(Qg + (size_t)r * 64 + sw, (char*)Qs + w * 1024);
  }
  __syncthreads();

  int ch = w >> 2, r0w = (w & 3) * 16, c0 = ch * 256;
  int rgrp = lane >> 4, cl = lane & 15;

  bf16x8 aF[2];
  aF[0] = lds_read_swz(Qs, r0w + cl, rgrp * 16);
  aF[1] = lds_read_swz(Qs, r0w + cl, 64 + rgrp * 16);

  f32x4 acc[16];
  f32x4 zero = {0.f, 0.f, 0.f, 0.f};
#pragma unroll
  for (int f = 0; f < 16; f++) {
    acc[f] = zero;
#pragma unroll
    for (int kbk = 0; kbk < 2; kbk++) {
      bf16x8 bF = lds_read_swz(Ks, c0 + 16 * f + cl, kbk * 64 + rgrp * 16);
      acc[f] = __builtin_amdgcn_mfma_f32_16x16x32_bf16(aF[kbk], bF, acc[f], 0, 0, 0);
    }
  }

  const float INV = 1.0f / 64.0f;  // scale(1/8) / T(8)
  if (ch == 0 && cl == 0) {
#pragma unroll
    for (int j = 0; j < 4; j++) s_tmax[r0w + rgrp * 4 + j] = acc[0][j] * INV;
  }
  __syncthreads();

  float tmv[4];
#pragma unroll
  for (int j = 0; j < 4; j++) tmv[j] = s_tmax[r0w + rgrp * 4 + j];

  float eb2 = eb2p[0];
  float rowsum[4] = {0.f, 0.f, 0.f, 0.f};

#pragma unroll
  for (int half = 0; half < 2; half++) {
    float tp[8][4];
#pragma unroll
    for (int f = 0; f < 8; f++)
#pragma unroll
      for (int j = 0; j < 4; j++) {
        float p = acc[half * 8 + f][j] * INV;
        tp[f][j] = fminf(p - tmv[j] + 1.0f, 3.0f);
        acc[half * 8 + f][j] = eb2;
      }
    // n-major exp-MLP: coefficients are uniform (scalar loads), 32 values/iter
    for (int n = 0; n < NE_; n++) {
      float w1n = ew1[n], b1n = eb1[n], w2n = ew2[n];
#pragma unroll
      for (int f = 0; f < 8; f++)
#pragma unroll
        for (int j = 0; j < 4; j++)
          acc[half * 8 + f][j] += w2n * fmaxf(tp[f][j] * w1n + b1n, 0.f);
    }
#pragma unroll
    for (int f = 0; f < 8; f++)
#pragma unroll
      for (int j = 0; j < 4; j++) {
        float xu = (tp[f][j] > -20.f) ? acc[half * 8 + f][j] : 0.f;
        acc[half * 8 + f][j] = xu;
        rowsum[j] += xu;
      }
  }

#pragma unroll
  for (int j = 0; j < 4; j++) {
    float s = rowsum[j];
    s += __shfl_xor(s, 1);
    s += __shfl_xor(s, 2);
    s += __shfl_xor(s, 4);
    s += __shfl_xor(s, 8);
    if (cl == 0) s_part[ch][r0w + rgrp * 4 + j] = s;
  }
  __syncthreads();

  if (tid < 64) {
    float part = s_part[0][tid] + s_part[1][tid];
    float pinv = invmlp(part, iw1, ib1, iw2, ib2p[0]);
    float pp2 = part * pinv;
    float fac = pinv;
    if (pp2 > 1.5f) fac *= invmlp(pp2, iw1, ib1, iw2, ib2p[0]);
    s_fac[tid] = fac;
  }
  __syncthreads();

  float* outb = out + ((size_t)bh * 512 + rt * 64) * 512;
#pragma unroll
  for (int j = 0; j < 4; j++) {
    int row = r0w + rgrp * 4 + j;
    float fac = s_fac[row];
#pragma unroll
    for (int f = 0; f < 16; f++)
      outb[(size_t)row * 512 + c0 + 16 * f + cl] = acc[f][j] * fac;
  }
}

extern "C" void kernel_launch(void* const* d_in, const int* in_sizes, int n_in,
                              void* d_out, int out_size, void* d_ws, size_t ws_size,
                              hipStream_t stream) {
  (void)in_sizes; (void)n_in; (void)out_size; (void)ws_size;
  const float* sx  = (const float*)d_in[0];
  const float* wq  = (const float*)d_in[1];
  const float* wk  = (const float*)d_in[2];
  const float* bq  = (const float*)d_in[3];
  const float* bk  = (const float*)d_in[4];
  const float* ew1 = (const float*)d_in[5];
  const float* eb1 = (const float*)d_in[6];
  const float* ew2 = (const float*)d_in[7];
  const float* eb2 = (const float*)d_in[8];
  const float* iw1 = (const float*)d_in[9];
  const float* ib1 = (const float*)d_in[10];
  const float* iw2 = (const float*)d_in[11];
  const float* ib2 = (const float*)d_in[12];
  unsigned short* wsu = (unsigned short*)d_ws;
  float* out = (float*)d_out;

  k_pre<<<2560, 256, 0, stream>>>(sx, wq, wk, wsu + XS_OFF, wsu + WQ_OFF, wsu + WK_OFF);
  k_proj<<<dim3(32, 4, 2), 256, 0, stream>>>(wsu + XS_OFF, wsu + WQ_OFF, bq, bk, wsu + QB_OFF);
  k_attn<<<dim3(8, 64), 512, 0, stream>>>(wsu + QB_OFF, wsu + KB_OFF,
                                          ew1, eb1, ew2, eb2, iw1, ib1, iw2, ib2, out);
}

// Round 2
// 76.464 us; speedup vs baseline: 1.2440x; 1.2440x over previous
//
#include <hip/hip_runtime.h>

// Shapes (fixed): T=8, S=512, B=8, D=512, H=8, hd=64, BH=64, NE=32, NI=64.
// out: (64, 512, 512) f32.
//
// Math reduction: sum_p telescopes to (sum_t Q_t)(sum_t K_t)^T * scale, so
//   p = (Xsum@Wq^T + 8 bq)(Xsum@Wk^T + 8 bk)^T / 64   (per bh batch, hd=64)
// The 1/64 is folded into Q at projection time. Epilogue MLP runs in packed
// f16 pairs with f32 dot2 accumulation (exact enough: 3x error margin).

#define T_  8
#define NE_ 32
#define NI_ 64

typedef __attribute__((ext_vector_type(8))) short bf16x8;
typedef __attribute__((ext_vector_type(4))) float f32x4;
typedef _Float16 h2 __attribute__((ext_vector_type(2)));

// workspace layout, in ushort elements
#define XS_OFF 0u        // Xsum bf16 (4096 x 512)
#define WQ_OFF 2097152u  // Wq bf16 (512 x 512)
#define WK_OFF 2359296u  // Wk bf16
#define QB_OFF 2621440u  // Q bf16 (64, 512, 64), pre-scaled by 1/64
#define KB_OFF 4718592u  // K bf16 (64, 512, 64)
#define EC_OFF 6815744u  // packed exp-MLP coefs: h2 w1[16], b1[16], w2[16]

__device__ inline unsigned short f2bf(float f) {
  union { float f; unsigned u; } v; v.f = f;
  unsigned r = v.u + 0x7FFFu + ((v.u >> 16) & 1u);
  return (unsigned short)(r >> 16);
}

__device__ inline void gload16(const void* g, void* l) {
  __builtin_amdgcn_global_load_lds(
      (const __attribute__((address_space(1))) void*)g,
      (__attribute__((address_space(3))) void*)l, 16, 0, 0);
}

// XOR-swizzled LDS read (k_proj only): 128-byte rows, slot ^ (row&7)
__device__ inline bf16x8 lds_read_swz(const unsigned short* base, int row, int byteoff) {
  int addr = row * 128 + (byteoff ^ ((row & 7) << 4));
  return *(const bf16x8*)((const char*)base + addr);
}

__device__ inline float invmlp(float x, const float* __restrict__ w1,
                               const float* __restrict__ b1,
                               const float* __restrict__ w2, float b2) {
  float a = b2;
  for (int n = 0; n < NI_; n++) a += w2[n] * fmaxf(x * w1[n] + b1[n], 0.0f);
  return a;
}

// ---------------------------------------------------------------------------
// Kernel 1: Xsum = sum_t sx[t] (f32->bf16), Wq/Wk casts, exp-MLP coef packing.
__global__ __launch_bounds__(256) void k_pre(
    const float* __restrict__ sx, const float* __restrict__ wq,
    const float* __restrict__ wk, const float* __restrict__ ew1,
    const float* __restrict__ eb1, const float* __restrict__ ew2,
    unsigned short* __restrict__ xs, unsigned short* __restrict__ wqb,
    unsigned short* __restrict__ wkb, unsigned short* __restrict__ ecu) {
  int bx = blockIdx.x, tid = threadIdx.x;
  if (bx < 2048) {
    size_t i = ((size_t)bx * 256 + tid) * 4;
    float4 a = *(const float4*)(sx + i);
#pragma unroll
    for (int t = 1; t < T_; t++) {
      float4 v = *(const float4*)(sx + (size_t)t * 2097152 + i);
      a.x += v.x; a.y += v.y; a.z += v.z; a.w += v.w;
    }
    ushort4 o; o.x = f2bf(a.x); o.y = f2bf(a.y); o.z = f2bf(a.z); o.w = f2bf(a.w);
    *(ushort4*)(xs + i) = o;
  } else if (bx < 2560) {
    const float* src = (bx < 2304) ? wq : wk;
    unsigned short* dst = (bx < 2304) ? wqb : wkb;
    int base = (bx < 2304) ? 2048 : 2304;
    size_t i = ((size_t)(bx - base) * 256 + tid) * 4;
    float4 a = *(const float4*)(src + i);
    ushort4 o; o.x = f2bf(a.x); o.y = f2bf(a.y); o.z = f2bf(a.z); o.w = f2bf(a.w);
    *(ushort4*)(dst + i) = o;
  } else {
    // pack exp-MLP coefs into half2: w1 pairs [0..15], b1 [16..31], w2 [32..47]
    if (tid < 16) {
      h2* ec = (h2*)ecu;
      h2 a, b, c;
      a[0] = (_Float16)ew1[2 * tid]; a[1] = (_Float16)ew1[2 * tid + 1];
      b[0] = (_Float16)eb1[2 * tid]; b[1] = (_Float16)eb1[2 * tid + 1];
      c[0] = (_Float16)ew2[2 * tid]; c[1] = (_Float16)ew2[2 * tid + 1];
      ec[tid] = a; ec[16 + tid] = b; ec[32 + tid] = c;
    }
  }
}

// ---------------------------------------------------------------------------
// Kernel 2: Y = Xsum(4096x512) @ W^T + 8*bias, bf16 out in (bh, s, dh) layout.
// z=0 (Q) additionally scaled by 1/64.  grid (32,4,2), 256 thr, 128x128 tile.
__global__ __launch_bounds__(256, 2) void k_proj(
    const unsigned short* __restrict__ xs, const unsigned short* __restrict__ wb,
    const float* __restrict__ bq, const float* __restrict__ bk,
    unsigned short* __restrict__ outb) {
  __shared__ unsigned short As[128 * 64];
  __shared__ unsigned short Bs[128 * 64];
  int tid = threadIdx.x;
  int lane = tid & 63, w = tid >> 6;
  int r0 = blockIdx.x * 128;
  int c0 = blockIdx.y * 128;
  int z = blockIdx.z;
  const unsigned short* W = wb + (size_t)z * 262144;
  const float* bias = z ? bk : bq;
  unsigned short* dst = outb + (size_t)z * 2097152;
  float sc = z ? 1.0f : (1.0f / 64.0f);

  int rgrp = lane >> 4, cl = lane & 15;
  int r0w = (w >> 1) * 64, c0w = (w & 1) * 64;

  f32x4 acc[4][4];
  f32x4 zero = {0.f, 0.f, 0.f, 0.f};
#pragma unroll
  for (int m = 0; m < 4; m++)
#pragma unroll
    for (int n = 0; n < 4; n++) acc[m][n] = zero;

  int rl = lane >> 3, slot = lane & 7;

  for (int kt = 0; kt < 8; kt++) {
    int k0 = kt * 64;
#pragma unroll
    for (int i = 0; i < 4; i++) {
      int chunk = w * 4 + i;
      int r = chunk * 8 + rl;
      int sw = (slot ^ (r & 7)) * 8;
      gload16(xs + (size_t)(r0 + r) * 512 + k0 + sw, (char*)As + chunk * 1024);
      gload16(W + (size_t)(c0 + r) * 512 + k0 + sw, (char*)Bs + chunk * 1024);
    }
    __syncthreads();
#pragma unroll
    for (int kb = 0; kb < 2; kb++) {
      bf16x8 af[4], bfr[4];
#pragma unroll
      for (int m = 0; m < 4; m++) af[m] = lds_read_swz(As, r0w + 16 * m + cl, kb * 64 + rgrp * 16);
#pragma unroll
      for (int n = 0; n < 4; n++) bfr[n] = lds_read_swz(Bs, c0w + 16 * n + cl, kb * 64 + rgrp * 16);
#pragma unroll
      for (int m = 0; m < 4; m++)
#pragma unroll
        for (int n = 0; n < 4; n++)
          acc[m][n] = __builtin_amdgcn_mfma_f32_16x16x32_bf16(af[m], bfr[n], acc[m][n], 0, 0, 0);
    }
    __syncthreads();
  }

#pragma unroll
  for (int n = 0; n < 4; n++) {
    int cg = c0 + c0w + 16 * n + cl;
    float bv = 8.0f * bias[cg];
    int h = cg >> 6, dh = cg & 63;
#pragma unroll
    for (int m = 0; m < 4; m++) {
#pragma unroll
      for (int j = 0; j < 4; j++) {
        int rg = r0 + r0w + 16 * m + rgrp * 4 + j;
        int s = rg >> 3, b = rg & 7;
        dst[((size_t)(b * 8 + h) * 512 + s) * 64 + dh] = f2bf((acc[m][n][j] + bv) * sc);
      }
    }
  }
}

// ---------------------------------------------------------------------------
// Kernel 3: per (32-row tile, bh): P = Q K^T (Q pre-scaled), fused epilogue.
// grid (16, 64), 256 thr = 4 waves: w&1 = rowstripe (16 rows), w>>1 = colhalf
// (256 cols).  Q/K fragments read straight from global (K panel is L2-hot).
__global__ __launch_bounds__(256, 4) void k_attn(
    const unsigned short* __restrict__ qb, const unsigned short* __restrict__ kb,
    const unsigned short* __restrict__ ecu, const float* __restrict__ eb2p,
    const float* __restrict__ iw1, const float* __restrict__ ib1,
    const float* __restrict__ iw2, const float* __restrict__ ib2p,
    float* __restrict__ out) {
  __shared__ float s_tmax[32];
  __shared__ float s_part[2][32];
  __shared__ float s_fac[32];

  int tid = threadIdx.x;
  int lane = tid & 63, w = tid >> 6;
  int rt = blockIdx.x, bh = blockIdx.y;
  int rs = w & 1, ch = w >> 1;
  int r0 = rt * 32;
  int c0 = ch * 256;
  int rgrp = lane >> 4, cl = lane & 15;

  const unsigned short* Kg = kb + (size_t)bh * (512 * 64);
  const unsigned short* Qg = qb + (size_t)bh * (512 * 64);

  // Q A-fragments for this wave's 16 rows (A row = cl, k-chunk = rgrp)
  const bf16x8* qrow = (const bf16x8*)(Qg + (size_t)(r0 + rs * 16 + cl) * 64);
  bf16x8 aF0 = qrow[rgrp];
  bf16x8 aF1 = qrow[4 + rgrp];

  f32x4 acc[16];
  f32x4 zero = {0.f, 0.f, 0.f, 0.f};
#pragma unroll
  for (int f = 0; f < 16; f++) {
    const bf16x8* krow = (const bf16x8*)(Kg + (size_t)(c0 + 16 * f + cl) * 64);
    bf16x8 b0 = krow[rgrp];
    bf16x8 b1 = krow[4 + rgrp];
    acc[f] = __builtin_amdgcn_mfma_f32_16x16x32_bf16(aF0, b0, zero, 0, 0, 0);
    acc[f] = __builtin_amdgcn_mfma_f32_16x16x32_bf16(aF1, b1, acc[f], 0, 0, 0);
  }

  // tmax - 1 from column 0 (colhalf 0, frag 0, cl==0)
  if (ch == 0 && cl == 0) {
#pragma unroll
    for (int j = 0; j < 4; j++) s_tmax[rs * 16 + rgrp * 4 + j] = acc[0][j] - 1.0f;
  }
  __syncthreads();

  float tm1[4];
#pragma unroll
  for (int j = 0; j < 4; j++) tm1[j] = s_tmax[rs * 16 + rgrp * 4 + j];

  // packed exp-MLP coefs (uniform; compiler keeps them scalar)
  const h2* ec = (const h2*)ecu;
  h2 W1[16], B1[16], W2[16];
#pragma unroll
  for (int n = 0; n < 16; n++) { W1[n] = ec[n]; B1[n] = ec[16 + n]; W2[n] = ec[32 + n]; }
  float eb2 = eb2p[0];
  h2 zh = {(_Float16)0.f, (_Float16)0.f};

  float rowsum[4] = {0.f, 0.f, 0.f, 0.f};
#pragma unroll
  for (int f = 0; f < 16; f++) {
#pragma unroll
    for (int j = 0; j < 4; j++) {
      float tp = fmaxf(fminf(acc[f][j] - tm1[j], 3.0f), -30.0f);
      _Float16 th = (_Float16)tp;
      h2 tph = {th, th};
      float a = eb2;
#pragma unroll
      for (int n = 0; n < 16; n++) {
        h2 hv = W1[n] * tph + B1[n];
        hv = __builtin_elementwise_max(hv, zh);
        a = __builtin_amdgcn_fdot2(W2[n], hv, a, false);
      }
      float xu = (tp > -20.0f) ? a : 0.0f;
      acc[f][j] = xu;
      rowsum[j] += xu;
    }
  }

  // row partial sums across the 16 cl lanes
#pragma unroll
  for (int j = 0; j < 4; j++) {
    float s = rowsum[j];
    s += __shfl_xor(s, 1);
    s += __shfl_xor(s, 2);
    s += __shfl_xor(s, 4);
    s += __shfl_xor(s, 8);
    if (cl == 0) s_part[ch][rs * 16 + rgrp * 4 + j] = s;
  }
  __syncthreads();

  if (tid < 32) {
    float part = s_part[0][tid] + s_part[1][tid];
    float pinv = invmlp(part, iw1, ib1, iw2, ib2p[0]);
    float pp2 = part * pinv;
    float fac = pinv;
    if (pp2 > 1.5f) fac *= invmlp(pp2, iw1, ib1, iw2, ib2p[0]);
    s_fac[tid] = fac;
  }
  __syncthreads();

  float* outb = out + ((size_t)bh * 512 + r0) * 512;
#pragma unroll
  for (int j = 0; j < 4; j++) {
    int row = rs * 16 + rgrp * 4 + j;
    float fac = s_fac[row];
#pragma unroll
    for (int f = 0; f < 16; f++)
      outb[(size_t)row * 512 + c0 + 16 * f + cl] = acc[f][j] * fac;
  }
}

extern "C" void kernel_launch(void* const* d_in, const int* in_sizes, int n_in,
                              void* d_out, int out_size, void* d_ws, size_t ws_size,
                              hipStream_t stream) {
  (void)in_sizes; (void)n_in; (void)out_size; (void)ws_size;
  const float* sx  = (const float*)d_in[0];
  const float* wq  = (const float*)d_in[1];
  const float* wk  = (const float*)d_in[2];
  const float* bq  = (const float*)d_in[3];
  const float* bk  = (const float*)d_in[4];
  const float* ew1 = (const float*)d_in[5];
  const float* eb1 = (const float*)d_in[6];
  const float* ew2 = (const float*)d_in[7];
  const float* eb2 = (const float*)d_in[8];
  const float* iw1 = (const float*)d_in[9];
  const float* ib1 = (const float*)d_in[10];
  const float* iw2 = (const float*)d_in[11];
  const float* ib2 = (const float*)d_in[12];
  unsigned short* wsu = (unsigned short*)d_ws;
  float* out = (float*)d_out;

  k_pre<<<2561, 256, 0, stream>>>(sx, wq, wk, ew1, eb1, ew2,
                                  wsu + XS_OFF, wsu + WQ_OFF, wsu + WK_OFF, wsu + EC_OFF);
  k_proj<<<dim3(32, 4, 2), 256, 0, stream>>>(wsu + XS_OFF, wsu + WQ_OFF, bq, bk, wsu + QB_OFF);
  k_attn<<<dim3(16, 64), 256, 0, stream>>>(wsu + QB_OFF, wsu + KB_OFF, wsu + EC_OFF,
                                           eb2, iw1, ib1, iw2, ib2, out);
}

// Round 3
// 60.756 us; speedup vs baseline: 1.5656x; 1.2585x over previous
//
#include <hip/hip_runtime.h>

// Shapes (fixed): T=8, S=512, B=8, D=512, H=8, hd=64, BH=64, NE=32, NI=64.
// out: (64, 512, 512) f32.
//
// Math reduction: sum_p telescopes to (sum_t Q_t)(sum_t K_t)^T * scale, so
//   p = (Xsum@Wq^T + 8 bq)(Xsum@Wk^T + 8 bk)^T / 64   (per bh batch, hd=64)
// The 1/64 is folded into Q at projection time.
//
// exp-MLP epilogue = piecewise-linear in tp (32 ReLU knots). Evaluated via a
// 4096-bucket uniform chord LUT over [-20,3] built on-device from the exact
// f32 MLP at bucket edges (chord == function on knot-free buckets; knot
// buckets err <~1.5e-3, well inside the error budget).

#define T_  8
#define NE_ 32
#define NI_ 64

#define LUT_N   4096
#define LUT_LO  -20.0f
#define LUT_HI  3.0f
#define LUT_INVW (LUT_N / (LUT_HI - LUT_LO))     // 4096/23
#define LUT_W    ((LUT_HI - LUT_LO) / LUT_N)

typedef __attribute__((ext_vector_type(8))) short bf16x8;
typedef __attribute__((ext_vector_type(4))) float f32x4;

// workspace layout, in ushort elements
#define XS_OFF 0u        // Xsum bf16 (4096 x 512)
#define WQ_OFF 2097152u  // Wq bf16 (512 x 512)
#define WK_OFF 2359296u  // Wk bf16
#define QB_OFF 2621440u  // Q bf16 (64, 512, 64), pre-scaled by 1/64
#define KB_OFF 4718592u  // K bf16 (64, 512, 64)
#define LUT_OFF 6815744u // float2 lut[4096] = 32 KB

__device__ inline unsigned short f2bf(float f) {
  union { float f; unsigned u; } v; v.f = f;
  unsigned r = v.u + 0x7FFFu + ((v.u >> 16) & 1u);
  return (unsigned short)(r >> 16);
}

__device__ inline void gload16(const void* g, void* l) {
  __builtin_amdgcn_global_load_lds(
      (const __attribute__((address_space(1))) void*)g,
      (__attribute__((address_space(3))) void*)l, 16, 0, 0);
}

// XOR-swizzled LDS read (k_proj only): 128-byte rows, slot ^ (row&7)
__device__ inline bf16x8 lds_read_swz(const unsigned short* base, int row, int byteoff) {
  int addr = row * 128 + (byteoff ^ ((row & 7) << 4));
  return *(const bf16x8*)((const char*)base + addr);
}

__device__ inline float invmlp(float x, const float* __restrict__ w1,
                               const float* __restrict__ b1,
                               const float* __restrict__ w2, float b2) {
  float a = b2;
  for (int n = 0; n < NI_; n++) a += w2[n] * fmaxf(x * w1[n] + b1[n], 0.0f);
  return a;
}

__device__ inline float expmlp_exact(float t, const float* __restrict__ w1,
                                     const float* __restrict__ b1,
                                     const float* __restrict__ w2, float b2) {
  float a = b2;
#pragma unroll
  for (int n = 0; n < NE_; n++) a += w2[n] * fmaxf(t * w1[n] + b1[n], 0.0f);
  return a;
}

// ---------------------------------------------------------------------------
// Kernel 1: Xsum = sum_t sx[t] (f32->bf16), Wq/Wk casts, exp-MLP chord LUT.
__global__ __launch_bounds__(256) void k_pre(
    const float* __restrict__ sx, const float* __restrict__ wq,
    const float* __restrict__ wk, const float* __restrict__ ew1,
    const float* __restrict__ eb1, const float* __restrict__ ew2,
    const float* __restrict__ eb2p,
    unsigned short* __restrict__ xs, unsigned short* __restrict__ wqb,
    unsigned short* __restrict__ wkb, float2* __restrict__ lut) {
  int bx = blockIdx.x, tid = threadIdx.x;
  if (bx < 2048) {
    size_t i = ((size_t)bx * 256 + tid) * 4;
    float4 a = *(const float4*)(sx + i);
#pragma unroll
    for (int t = 1; t < T_; t++) {
      float4 v = *(const float4*)(sx + (size_t)t * 2097152 + i);
      a.x += v.x; a.y += v.y; a.z += v.z; a.w += v.w;
    }
    ushort4 o; o.x = f2bf(a.x); o.y = f2bf(a.y); o.z = f2bf(a.z); o.w = f2bf(a.w);
    *(ushort4*)(xs + i) = o;
  } else if (bx < 2560) {
    const float* src = (bx < 2304) ? wq : wk;
    unsigned short* dst = (bx < 2304) ? wqb : wkb;
    int base = (bx < 2304) ? 2048 : 2304;
    size_t i = ((size_t)(bx - base) * 256 + tid) * 4;
    float4 a = *(const float4*)(src + i);
    ushort4 o; o.x = f2bf(a.x); o.y = f2bf(a.y); o.z = f2bf(a.z); o.w = f2bf(a.w);
    *(ushort4*)(dst + i) = o;
  } else {
    // chord LUT: bucket i over [t_i, t_{i+1}], edges evaluated identically by
    // neighbors -> bit-exact continuity.
    int i = (bx - 2560) * 256 + tid;
    float b2 = eb2p[0];
    float tl = fmaf((float)i, LUT_W, LUT_LO);
    float th = fmaf((float)(i + 1), LUT_W, LUT_LO);
    float el = expmlp_exact(tl, ew1, eb1, ew2, b2);
    float eh = expmlp_exact(th, ew1, eb1, ew2, b2);
    float alpha = (eh - el) * LUT_INVW;
    float beta = fmaf(-alpha, tl, el);
    lut[i] = make_float2(alpha, beta);
  }
}

// ---------------------------------------------------------------------------
// Kernel 2: Y = Xsum(4096x512) @ W^T + 8*bias, bf16 out in (bh, s, dh) layout.
// z=0 (Q) additionally scaled by 1/64.  grid (32,4,2), 256 thr, 128x128 tile.
__global__ __launch_bounds__(256, 2) void k_proj(
    const unsigned short* __restrict__ xs, const unsigned short* __restrict__ wb,
    const float* __restrict__ bq, const float* __restrict__ bk,
    unsigned short* __restrict__ outb) {
  __shared__ unsigned short As[128 * 64];
  __shared__ unsigned short Bs[128 * 64];
  int tid = threadIdx.x;
  int lane = tid & 63, w = tid >> 6;
  int r0 = blockIdx.x * 128;
  int c0 = blockIdx.y * 128;
  int z = blockIdx.z;
  const unsigned short* W = wb + (size_t)z * 262144;
  const float* bias = z ? bk : bq;
  unsigned short* dst = outb + (size_t)z * 2097152;
  float sc = z ? 1.0f : (1.0f / 64.0f);

  int rgrp = lane >> 4, cl = lane & 15;
  int r0w = (w >> 1) * 64, c0w = (w & 1) * 64;

  f32x4 acc[4][4];
  f32x4 zero = {0.f, 0.f, 0.f, 0.f};
#pragma unroll
  for (int m = 0; m < 4; m++)
#pragma unroll
    for (int n = 0; n < 4; n++) acc[m][n] = zero;

  int rl = lane >> 3, slot = lane & 7;

  for (int kt = 0; kt < 8; kt++) {
    int k0 = kt * 64;
#pragma unroll
    for (int i = 0; i < 4; i++) {
      int chunk = w * 4 + i;
      int r = chunk * 8 + rl;
      int sw = (slot ^ (r & 7)) * 8;
      gload16(xs + (size_t)(r0 + r) * 512 + k0 + sw, (char*)As + chunk * 1024);
      gload16(W + (size_t)(c0 + r) * 512 + k0 + sw, (char*)Bs + chunk * 1024);
    }
    __syncthreads();
#pragma unroll
    for (int kb = 0; kb < 2; kb++) {
      bf16x8 af[4], bfr[4];
#pragma unroll
      for (int m = 0; m < 4; m++) af[m] = lds_read_swz(As, r0w + 16 * m + cl, kb * 64 + rgrp * 16);
#pragma unroll
      for (int n = 0; n < 4; n++) bfr[n] = lds_read_swz(Bs, c0w + 16 * n + cl, kb * 64 + rgrp * 16);
#pragma unroll
      for (int m = 0; m < 4; m++)
#pragma unroll
        for (int n = 0; n < 4; n++)
          acc[m][n] = __builtin_amdgcn_mfma_f32_16x16x32_bf16(af[m], bfr[n], acc[m][n], 0, 0, 0);
    }
    __syncthreads();
  }

#pragma unroll
  for (int n = 0; n < 4; n++) {
    int cg = c0 + c0w + 16 * n + cl;
    float bv = 8.0f * bias[cg];
    int h = cg >> 6, dh = cg & 63;
#pragma unroll
    for (int m = 0; m < 4; m++) {
#pragma unroll
      for (int j = 0; j < 4; j++) {
        int rg = r0 + r0w + 16 * m + rgrp * 4 + j;
        int s = rg >> 3, b = rg & 7;
        dst[((size_t)(b * 8 + h) * 512 + s) * 64 + dh] = f2bf((acc[m][n][j] + bv) * sc);
      }
    }
  }
}

// ---------------------------------------------------------------------------
// Kernel 3: per (32-row tile, bh): P = Q K^T (Q pre-scaled), LUT epilogue.
// grid (16, 64), 512 thr = 8 waves: w&1 = rowstripe (16 rows), w>>1 = col
// strip (128 cols).  Q/K fragments read straight from global (L2-hot).
__global__ __launch_bounds__(512, 4) void k_attn(
    const unsigned short* __restrict__ qb, const unsigned short* __restrict__ kb,
    const float2* __restrict__ lutg,
    const float* __restrict__ iw1, const float* __restrict__ ib1,
    const float* __restrict__ iw2, const float* __restrict__ ib2p,
    float* __restrict__ out) {
  __shared__ float2 Lut[LUT_N];   // 32 KB
  __shared__ float s_tmax[32];
  __shared__ float s_part[4][32];
  __shared__ float s_fac[32];

  int tid = threadIdx.x;
  int lane = tid & 63, w = tid >> 6;
  int rt = blockIdx.x, bh = blockIdx.y;
  int rs = w & 1, ch = w >> 1;
  int r0 = rt * 32;
  int c0 = ch * 128;
  int rgrp = lane >> 4, cl = lane & 15;

  // stage LUT into LDS (linear, 32 chunks of 1 KB across 8 waves)
#pragma unroll
  for (int i = 0; i < 4; i++) {
    int chunk = w * 4 + i;
    gload16((const char*)lutg + chunk * 1024 + lane * 16, (char*)Lut + chunk * 1024);
  }

  const unsigned short* Kg = kb + (size_t)bh * (512 * 64);
  const unsigned short* Qg = qb + (size_t)bh * (512 * 64);

  // Q A-fragments for this wave's 16 rows (A row = cl, k-chunk = rgrp)
  const bf16x8* qrow = (const bf16x8*)(Qg + (size_t)(r0 + rs * 16 + cl) * 64);
  bf16x8 aF0 = qrow[rgrp];
  bf16x8 aF1 = qrow[4 + rgrp];

  f32x4 acc[8];
  f32x4 zero = {0.f, 0.f, 0.f, 0.f};
#pragma unroll
  for (int f = 0; f < 8; f++) {
    const bf16x8* krow = (const bf16x8*)(Kg + (size_t)(c0 + 16 * f + cl) * 64);
    bf16x8 b0 = krow[rgrp];
    bf16x8 b1 = krow[4 + rgrp];
    acc[f] = __builtin_amdgcn_mfma_f32_16x16x32_bf16(aF0, b0, zero, 0, 0, 0);
    acc[f] = __builtin_amdgcn_mfma_f32_16x16x32_bf16(aF1, b1, acc[f], 0, 0, 0);
  }

  // tmax - 1 from column 0 (strip 0, frag 0, cl==0)
  if (ch == 0 && cl == 0) {
#pragma unroll
    for (int j = 0; j < 4; j++) s_tmax[rs * 16 + rgrp * 4 + j] = acc[0][j] - 1.0f;
  }
  __syncthreads();  // covers s_tmax + LUT gloads (barrier drains vmcnt)

  float tm1[4];
#pragma unroll
  for (int j = 0; j < 4; j++) tm1[j] = s_tmax[rs * 16 + rgrp * 4 + j];

  const float C0 = -LUT_LO * LUT_INVW;
  float rowsum[4] = {0.f, 0.f, 0.f, 0.f};
#pragma unroll
  for (int f = 0; f < 8; f++) {
#pragma unroll
    for (int j = 0; j < 4; j++) {
      float tp = fminf(acc[f][j] - tm1[j], 3.0f);
      float u = fmaf(tp, LUT_INVW, C0);
      u = fminf(fmaxf(u, 0.0f), (float)(LUT_N - 1));  // v_med3
      float2 ab = Lut[(int)u];
      float xu = fmaf(ab.x, tp, ab.y);
      xu = (tp > -20.0f) ? xu : 0.0f;
      acc[f][j] = xu;
      rowsum[j] += xu;
    }
  }

  // row partial sums across the 16 cl lanes
#pragma unroll
  for (int j = 0; j < 4; j++) {
    float s = rowsum[j];
    s += __shfl_xor(s, 1);
    s += __shfl_xor(s, 2);
    s += __shfl_xor(s, 4);
    s += __shfl_xor(s, 8);
    if (cl == 0) s_part[ch][rs * 16 + rgrp * 4 + j] = s;
  }
  __syncthreads();

  if (tid < 32) {
    float part = s_part[0][tid] + s_part[1][tid] + s_part[2][tid] + s_part[3][tid];
    float pinv = invmlp(part, iw1, ib1, iw2, ib2p[0]);
    float pp2 = part * pinv;
    float fac = pinv;
    if (pp2 > 1.5f) fac *= invmlp(pp2, iw1, ib1, iw2, ib2p[0]);
    s_fac[tid] = fac;
  }
  __syncthreads();

  float* outb = out + ((size_t)bh * 512 + r0) * 512;
#pragma unroll
  for (int j = 0; j < 4; j++) {
    int row = rs * 16 + rgrp * 4 + j;
    float fac = s_fac[row];
#pragma unroll
    for (int f = 0; f < 8; f++)
      outb[(size_t)row * 512 + c0 + 16 * f + cl] = acc[f][j] * fac;
  }
}

extern "C" void kernel_launch(void* const* d_in, const int* in_sizes, int n_in,
                              void* d_out, int out_size, void* d_ws, size_t ws_size,
                              hipStream_t stream) {
  (void)in_sizes; (void)n_in; (void)out_size; (void)ws_size;
  const float* sx  = (const float*)d_in[0];
  const float* wq  = (const float*)d_in[1];
  const float* wk  = (const float*)d_in[2];
  const float* bq  = (const float*)d_in[3];
  const float* bk  = (const float*)d_in[4];
  const float* ew1 = (const float*)d_in[5];
  const float* eb1 = (const float*)d_in[6];
  const float* ew2 = (const float*)d_in[7];
  const float* eb2 = (const float*)d_in[8];
  const float* iw1 = (const float*)d_in[9];
  const float* ib1 = (const float*)d_in[10];
  const float* iw2 = (const float*)d_in[11];
  const float* ib2 = (const float*)d_in[12];
  unsigned short* wsu = (unsigned short*)d_ws;
  float2* lut = (float2*)(wsu + LUT_OFF);
  float* out = (float*)d_out;

  k_pre<<<2576, 256, 0, stream>>>(sx, wq, wk, ew1, eb1, ew2, eb2,
                                  wsu + XS_OFF, wsu + WQ_OFF, wsu + WK_OFF, lut);
  k_proj<<<dim3(32, 4, 2), 256, 0, stream>>>(wsu + XS_OFF, wsu + WQ_OFF, bq, bk, wsu + QB_OFF);
  k_attn<<<dim3(16, 64), 512, 0, stream>>>(wsu + QB_OFF, wsu + KB_OFF, lut,
                                           iw1, ib1, iw2, ib2, out);
}